// Round 1
// baseline (809.879 us; speedup 1.0000x reference)
//
#include <hip/hip_runtime.h>

typedef unsigned short u16;
typedef unsigned int u32;
typedef __attribute__((ext_vector_type(4))) float f32x4;
typedef __attribute__((ext_vector_type(8))) short s16x8;

#define DEVI static __device__ __forceinline__

// B=2, S=2048, E=2048, H=16, D=128, MP=4, local=512; qkv cols: [q(512) v(512) k(512)] x4
// scale 1/sqrt(128) folded into q during rope.

DEVI u16 f2bf(float f) {
  u32 u = __float_as_uint(f);
  return (u16)((u + 0x7FFFu + ((u >> 16) & 1u)) >> 16);  // round-to-nearest-even
}
DEVI float bf2f(u16 h) { return __uint_as_float(((u32)h) << 16); }

DEVI void async_copy16(const u16* g, u16* l) {
  // dest = wave-uniform LDS base + lane*16 (gfx950 global_load_lds_dwordx4)
  __builtin_amdgcn_global_load_lds((__attribute__((address_space(1))) void*)g,
                                   (__attribute__((address_space(3))) void*)l, 16, 0, 0);
}

__global__ __launch_bounds__(256) void cast_bf16_kernel(const float* __restrict__ src,
                                                        u16* __restrict__ dst, int n4) {
  int i = blockIdx.x * 256 + threadIdx.x;
  if (i < n4) {
    const float4 v = ((const float4*)src)[i];
    ushort4 o;
    o.x = f2bf(v.x); o.y = f2bf(v.y); o.z = f2bf(v.z); o.w = f2bf(v.w);
    ((ushort4*)dst)[i] = o;
  }
}

// C[m,n] = sum_k A[m,k]*B[n,k]; A,B row-major bf16 with K contiguous (B^T GEMM).
// 128x128 block tile, BK=32, 4 waves as 2x2 of 64x64, 16x16x32 MFMA 4x4 frags/wave.
// EPI=0: C fp32 plain store.  EPI=1: scatter qkv -> q[B,H,S,D], k[B,H,S,D], v^T[B,H,D,S] bf16.
template <int EPI>
__global__ __launch_bounds__(256, 2) void gemm_bt_kernel(
    const u16* __restrict__ A, const u16* __restrict__ Bm, int K, int N,
    float* __restrict__ C, u16* __restrict__ qo, u16* __restrict__ ko, u16* __restrict__ vo) {
  __shared__ __attribute__((aligned(16))) u16 As[128 * 32];
  __shared__ __attribute__((aligned(16))) u16 Bs[128 * 32];
  const int tid = threadIdx.x;
  const int w = tid >> 6, lane = tid & 63;
  const int quad = lane >> 4, l16 = lane & 15;
  const int wrow = (w >> 1) * 64, wcol = (w & 1) * 64;
  const long tileM = (long)blockIdx.y * 128;
  const long tileN = (long)blockIdx.x * 128;

  f32x4 acc[4][4];
#pragma unroll
  for (int i = 0; i < 4; ++i)
#pragma unroll
    for (int j = 0; j < 4; ++j) acc[i][j] = f32x4{0.f, 0.f, 0.f, 0.f};

  const int ldr = lane >> 2;         // row within 16-row chunk (4 lanes/row)
  const int ldc = (lane & 3) * 8;    // col start (8 bf16 = 16B per lane)

  for (int k0 = 0; k0 < K; k0 += 32) {
    __syncthreads();
#pragma unroll
    for (int c = 0; c < 2; ++c) {
      const int r0 = (w * 2 + c) * 16;  // 16 rows per wave-call, 1KB LDS chunk
      async_copy16(A + (tileM + r0 + ldr) * (long)K + (k0 + ldc), As + r0 * 32);
      async_copy16(Bm + (tileN + r0 + ldr) * (long)K + (k0 + ldc), Bs + r0 * 32);
    }
    __builtin_amdgcn_s_waitcnt(0);
    __syncthreads();

    s16x8 af[4], bfr[4];
#pragma unroll
    for (int i = 0; i < 4; ++i)
      af[i] = *(const s16x8*)(As + (wrow + i * 16 + l16) * 32 + quad * 8);
#pragma unroll
    for (int j = 0; j < 4; ++j)
      bfr[j] = *(const s16x8*)(Bs + (wcol + j * 16 + l16) * 32 + quad * 8);
#pragma unroll
    for (int i = 0; i < 4; ++i)
#pragma unroll
      for (int j = 0; j < 4; ++j)
        acc[i][j] = __builtin_amdgcn_mfma_f32_16x16x32_bf16(af[i], bfr[j], acc[i][j], 0, 0, 0);
  }

#pragma unroll
  for (int i = 0; i < 4; ++i) {
#pragma unroll
    for (int j = 0; j < 4; ++j) {
#pragma unroll
      for (int r = 0; r < 4; ++r) {
        const long row = tileM + wrow + i * 16 + quad * 4 + r;  // C row = quad*4+reg
        const long col = tileN + wcol + j * 16 + l16;           // C col = lane&15
        const float v = acc[i][j][r];
        if (EPI == 0) {
          C[row * N + col] = v;
        } else {
          const int b = (int)(row >> 11), s = (int)(row & 2047);
          const int cl = (int)col;
          const int mp = cl / 1536;
          const int cc = cl - mp * 1536;
          const int part = cc >> 9;         // 0:q 1:v 2:k
          const int idx = cc & 511;
          const int head = mp * 4 + (idx >> 7);
          const int dim = idx & 127;
          const long bh = b * 16 + head;
          const u16 bv = f2bf(v);
          if (part == 0)      qo[(bh * 2048 + s) * 128 + dim] = bv;
          else if (part == 2) ko[(bh * 2048 + s) * 128 + dim] = bv;
          else                vo[(bh * 128 + dim) * 2048 + s] = bv;  // v stored transposed
        }
      }
    }
  }
}

// In-place rope on q (blockIdx.y=0, also applies 1/sqrt(D)) and k (blockIdx.y=1).
// One thread per dim-pair; 4 rows per 256-thread block.
__global__ __launch_bounds__(256) void rope_kernel(u16* __restrict__ q, u16* __restrict__ k) {
  const int tid = threadIdx.x;
  const long row = (long)blockIdx.x * 4 + (tid >> 6);  // row in [0, B*H*S)
  const int p = tid & 63;                              // pair index 0..63
  const int s = (int)(row & 2047);                     // position
  u16* base = (blockIdx.y == 0 ? q : k) + row * 128 + p * 2;
  const float scale = (blockIdx.y == 0) ? 0.08838834764831845f : 1.0f;
  const float x0 = bf2f(base[0]), x1 = bf2f(base[1]);
  float y0, y1;
  if (p < 32) {
    // inv_freq = 10000^(-2p/64) = 2^(-p/32 * log2(10000))
    const float inv = exp2f((float)p * (-13.287712379549449f / 32.0f));
    const float fr = (float)s * inv;
    const float sn = sinf(fr), cs = cosf(fr);
    y0 = (x0 * cs - x1 * sn) * scale;
    y1 = (x1 * cs + x0 * sn) * scale;
  } else {
    y0 = x0 * scale;
    y1 = x1 * scale;
  }
  base[0] = f2bf(y0);
  base[1] = f2bf(y1);
}

// Flash attention. Block = 64 q rows (4 independent waves x 16 rows), grid (S/64, B*H).
// K,V fragments read directly from global (L2-resident per (b,h)); no __syncthreads.
__global__ __launch_bounds__(256, 2) void attn_kernel(
    const u16* __restrict__ q, const u16* __restrict__ k,
    const u16* __restrict__ vT, u16* __restrict__ out) {
  __shared__ __attribute__((aligned(16))) u16 Ps[4][16 * 32];  // per-wave P transpose buf
  const int tid = threadIdx.x;
  const int w = tid >> 6, lane = tid & 63;
  const int quad = lane >> 4, l16 = lane & 15;
  const int qt = blockIdx.x, bh = blockIdx.y;
  const int qbase = qt * 64 + w * 16;

  const u16* qp = q + ((long)bh * 2048 + qbase) * 128;
  const u16* kp = k + (long)bh * 2048 * 128;
  const u16* vp = vT + (long)bh * 128 * 2048;

  s16x8 qf[4];  // A-frag: Q[m=l16][kdim = c*32 + quad*8 + j]
#pragma unroll
  for (int c = 0; c < 4; ++c)
    qf[c] = *(const s16x8*)(qp + l16 * 128 + c * 32 + quad * 8);

  f32x4 acc[8];
#pragma unroll
  for (int d = 0; d < 8; ++d) acc[d] = f32x4{0.f, 0.f, 0.f, 0.f};
  float mrun[4], lrun[4];
#pragma unroll
  for (int r = 0; r < 4; ++r) { mrun[r] = -1e30f; lrun[r] = 0.f; }

  const int ntiles = ((qbase + 15) >> 5) + 1;  // causal bound for this wave
  for (int t = 0; t < ntiles; ++t) {
    const int k0 = t * 32;
    f32x4 sc0 = f32x4{0.f, 0.f, 0.f, 0.f}, sc1 = sc0;
#pragma unroll
    for (int c = 0; c < 4; ++c) {  // B-frag: K[n=key=l16][kdim = c*32+quad*8+j]
      const s16x8 kf0 = *(const s16x8*)(kp + (long)(k0 + l16) * 128 + c * 32 + quad * 8);
      const s16x8 kf1 = *(const s16x8*)(kp + (long)(k0 + 16 + l16) * 128 + c * 32 + quad * 8);
      sc0 = __builtin_amdgcn_mfma_f32_16x16x32_bf16(qf[c], kf0, sc0, 0, 0, 0);
      sc1 = __builtin_amdgcn_mfma_f32_16x16x32_bf16(qf[c], kf1, sc1, 0, 0, 0);
    }
    // causal mask: C row = qbase + quad*4 + r, col = k0 + {0,16} + l16
    const int colb = k0 + l16;
#pragma unroll
    for (int r = 0; r < 4; ++r) {
      const int rowr = qbase + quad * 4 + r;
      if (colb > rowr) sc0[r] = -1e30f;
      if (colb + 16 > rowr) sc1[r] = -1e30f;
    }
    f32x4 p0, p1;
    float alpha[4];
#pragma unroll
    for (int r = 0; r < 4; ++r) {
      float mx = fmaxf(sc0[r], sc1[r]);
#pragma unroll
      for (int off = 1; off < 16; off <<= 1) mx = fmaxf(mx, __shfl_xor(mx, off, 64));
      const float mnew = fmaxf(mrun[r], mx);
      alpha[r] = __expf(mrun[r] - mnew);  // first iter: exp(-1e30-x)=0
      mrun[r] = mnew;
      p0[r] = __expf(sc0[r] - mnew);
      p1[r] = __expf(sc1[r] - mnew);
      float sm = p0[r] + p1[r];
#pragma unroll
      for (int off = 1; off < 16; off <<= 1) sm += __shfl_xor(sm, off, 64);
      lrun[r] = lrun[r] * alpha[r] + sm;
    }
#pragma unroll
    for (int d = 0; d < 8; ++d)
#pragma unroll
      for (int r = 0; r < 4; ++r) acc[d][r] *= alpha[r];
    // P: C-layout -> A-layout via per-wave LDS (same-wave in-order DS + waitcnt)
#pragma unroll
    for (int r = 0; r < 4; ++r) {
      Ps[w][(quad * 4 + r) * 32 + l16] = f2bf(p0[r]);
      Ps[w][(quad * 4 + r) * 32 + 16 + l16] = f2bf(p1[r]);
    }
    __builtin_amdgcn_s_waitcnt(0);
    const s16x8 pf = *(const s16x8*)(&Ps[w][l16 * 32 + quad * 8]);
#pragma unroll
    for (int d = 0; d < 8; ++d) {  // B-frag: V^T[n=dim][key = quad*8+j] contiguous
      const s16x8 vf = *(const s16x8*)(vp + (long)(d * 16 + l16) * 2048 + k0 + quad * 8);
      acc[d] = __builtin_amdgcn_mfma_f32_16x16x32_bf16(pf, vf, acc[d], 0, 0, 0);
    }
  }
  const int b = bh >> 4, h = bh & 15;
  u16* op = out + ((long)b * 2048 + qbase) * 2048 + h * 128;
#pragma unroll
  for (int d = 0; d < 8; ++d)
#pragma unroll
    for (int r = 0; r < 4; ++r) {
      const float v = acc[d][r] / lrun[r];
      op[(long)(quad * 4 + r) * 2048 + d * 16 + l16] = f2bf(v);
    }
}

extern "C" void kernel_launch(void* const* d_in, const int* in_sizes, int n_in,
                              void* d_out, int out_size, void* d_ws, size_t ws_size,
                              hipStream_t stream) {
  const float* hidden = (const float*)d_in[0];  // [2,2048,2048]
  const float* w_qkv = (const float*)d_in[1];   // [6144,2048]
  const float* w_out = (const float*)d_in[2];   // [2048,2048]
  float* out = (float*)d_out;                   // [2,2048,2048] fp32
  char* ws = (char*)d_ws;

  // workspace layout (112 MB total, all 16B aligned)
  u16* hid_b  = (u16*)(ws + (size_t)0);          // 16.8 MB  hidden bf16
  u16* wqkv_b = (u16*)(ws + (size_t)16777216);   // 25.2 MB  w_qkv bf16
  u16* wout_b = (u16*)(ws + (size_t)41943040);   //  8.4 MB  w_out bf16
  u16* qb     = (u16*)(ws + (size_t)50331648);   // 16.8 MB  q [B,H,S,D]
  u16* kb     = (u16*)(ws + (size_t)67108864);   // 16.8 MB  k [B,H,S,D]
  u16* vb     = (u16*)(ws + (size_t)83886080);   // 16.8 MB  v^T [B,H,D,S]
  u16* ao     = (u16*)(ws + (size_t)100663296);  // 16.8 MB  attn out [B,S,E]

  cast_bf16_kernel<<<8192, 256, 0, stream>>>(hidden, hid_b, 2097152);
  cast_bf16_kernel<<<12288, 256, 0, stream>>>(w_qkv, wqkv_b, 3145728);
  cast_bf16_kernel<<<4096, 256, 0, stream>>>(w_out, wout_b, 1048576);

  // qkv projection, fused split/transpose epilogue
  gemm_bt_kernel<1><<<dim3(48, 32), 256, 0, stream>>>(hid_b, wqkv_b, 2048, 6144,
                                                      nullptr, qb, kb, vb);
  // rope q (scaled) and k, in place
  rope_kernel<<<dim3(16384, 2), 256, 0, stream>>>(qb, kb);
  // causal flash attention
  attn_kernel<<<dim3(32, 32), 256, 0, stream>>>(qb, kb, vb, ao);
  // output projection -> fp32
  gemm_bt_kernel<0><<<dim3(16, 32), 256, 0, stream>>>(ao, wout_b, 2048, 2048,
                                                      out, nullptr, nullptr, nullptr);
}

// Round 2
// 445.958 us; speedup vs baseline: 1.8160x; 1.8160x over previous
//
#include <hip/hip_runtime.h>

typedef unsigned short u16;
typedef unsigned int u32;
typedef __attribute__((ext_vector_type(4))) float f32x4;
typedef __attribute__((ext_vector_type(8))) short s16x8;

#define DEVI static __device__ __forceinline__

// B=2, S=2048, E=2048, H=16, D=128, MP=4, local=512; qkv cols: [q(512) v(512) k(512)] x4
// scale (1/sqrt(128))*log2(e) folded into q during rope; softmax in exp2 domain.

DEVI u16 f2bf(float f) {
  u32 u = __float_as_uint(f);
  return (u16)((u + 0x7FFFu + ((u >> 16) & 1u)) >> 16);  // round-to-nearest-even
}
DEVI float bf2f(u16 h) { return __uint_as_float(((u32)h) << 16); }

DEVI void async_copy16(const u16* g, u16* l) {
  // dest = wave-uniform LDS base + lane*16 (gfx950 global_load_lds_dwordx4)
  __builtin_amdgcn_global_load_lds((__attribute__((address_space(1))) void*)g,
                                   (__attribute__((address_space(3))) void*)l, 16, 0, 0);
}

__global__ __launch_bounds__(256) void cast_bf16_kernel(const float* __restrict__ src,
                                                        u16* __restrict__ dst, int n4) {
  int i = blockIdx.x * 256 + threadIdx.x;
  if (i < n4) {
    const float4 v = ((const float4*)src)[i];
    ushort4 o;
    o.x = f2bf(v.x); o.y = f2bf(v.y); o.z = f2bf(v.z); o.w = f2bf(v.w);
    ((ushort4*)dst)[i] = o;
  }
}

// C[m,n] = sum_k A[m,k]*B[n,k]; A,B row-major bf16 with K contiguous (B^T GEMM).
// 128x128 block tile, BK=32, 4 waves as 2x2 of 64x64, 16x16x32 MFMA 4x4 frags/wave.
// EPI=0: C fp32 plain store.  EPI=1: scatter qkv -> q[B,H,S,D], k[B,H,S,D], v^T[B,H,D,S] bf16.
template <int EPI>
__global__ __launch_bounds__(256, 2) void gemm_bt_kernel(
    const u16* __restrict__ A, const u16* __restrict__ Bm, int K, int N,
    float* __restrict__ C, u16* __restrict__ qo, u16* __restrict__ ko, u16* __restrict__ vo) {
  __shared__ __attribute__((aligned(16))) u16 As[128 * 32];
  __shared__ __attribute__((aligned(16))) u16 Bs[128 * 32];
  const int tid = threadIdx.x;
  const int w = tid >> 6, lane = tid & 63;
  const int quad = lane >> 4, l16 = lane & 15;
  const int wrow = (w >> 1) * 64, wcol = (w & 1) * 64;
  const long tileM = (long)blockIdx.y * 128;
  const long tileN = (long)blockIdx.x * 128;

  f32x4 acc[4][4];
#pragma unroll
  for (int i = 0; i < 4; ++i)
#pragma unroll
    for (int j = 0; j < 4; ++j) acc[i][j] = f32x4{0.f, 0.f, 0.f, 0.f};

  const int ldr = lane >> 2;         // row within 16-row chunk (4 lanes/row)
  const int ldc = (lane & 3) * 8;    // col start (8 bf16 = 16B per lane)

  for (int k0 = 0; k0 < K; k0 += 32) {
    __syncthreads();
#pragma unroll
    for (int c = 0; c < 2; ++c) {
      const int r0 = (w * 2 + c) * 16;  // 16 rows per wave-call, 1KB LDS chunk
      async_copy16(A + (tileM + r0 + ldr) * (long)K + (k0 + ldc), As + r0 * 32);
      async_copy16(Bm + (tileN + r0 + ldr) * (long)K + (k0 + ldc), Bs + r0 * 32);
    }
    __builtin_amdgcn_s_waitcnt(0x0f70);  // vmcnt(0) only
    __syncthreads();

    s16x8 af[4], bfr[4];
#pragma unroll
    for (int i = 0; i < 4; ++i)
      af[i] = *(const s16x8*)(As + (wrow + i * 16 + l16) * 32 + quad * 8);
#pragma unroll
    for (int j = 0; j < 4; ++j)
      bfr[j] = *(const s16x8*)(Bs + (wcol + j * 16 + l16) * 32 + quad * 8);
#pragma unroll
    for (int i = 0; i < 4; ++i)
#pragma unroll
      for (int j = 0; j < 4; ++j)
        acc[i][j] = __builtin_amdgcn_mfma_f32_16x16x32_bf16(af[i], bfr[j], acc[i][j], 0, 0, 0);
  }

#pragma unroll
  for (int i = 0; i < 4; ++i) {
#pragma unroll
    for (int j = 0; j < 4; ++j) {
#pragma unroll
      for (int r = 0; r < 4; ++r) {
        const long row = tileM + wrow + i * 16 + quad * 4 + r;  // C row = quad*4+reg
        const long col = tileN + wcol + j * 16 + l16;           // C col = lane&15
        const float v = acc[i][j][r];
        if (EPI == 0) {
          C[row * N + col] = v;
        } else {
          const int b = (int)(row >> 11), s = (int)(row & 2047);
          const int cl = (int)col;
          const int mp = cl / 1536;
          const int cc = cl - mp * 1536;
          const int part = cc >> 9;         // 0:q 1:v 2:k
          const int idx = cc & 511;
          const int head = mp * 4 + (idx >> 7);
          const int dim = idx & 127;
          const long bh = b * 16 + head;
          const u16 bv = f2bf(v);
          if (part == 0)      qo[(bh * 2048 + s) * 128 + dim] = bv;
          else if (part == 2) ko[(bh * 2048 + s) * 128 + dim] = bv;
          else                vo[(bh * 128 + dim) * 2048 + s] = bv;  // v stored transposed
        }
      }
    }
  }
}

// In-place rope on q (blockIdx.y=0, also applies log2e/sqrt(D)) and k (blockIdx.y=1).
__global__ __launch_bounds__(256) void rope_kernel(u16* __restrict__ q, u16* __restrict__ k) {
  const int tid = threadIdx.x;
  const long row = (long)blockIdx.x * 4 + (tid >> 6);  // row in [0, B*H*S)
  const int p = tid & 63;                              // pair index 0..63
  const int s = (int)(row & 2047);                     // position
  u16* base = (blockIdx.y == 0 ? q : k) + row * 128 + p * 2;
  // q scale = 1/sqrt(128) * log2(e)  (softmax runs in exp2 domain)
  const float scale = (blockIdx.y == 0) ? 0.12751743f : 1.0f;
  const float x0 = bf2f(base[0]), x1 = bf2f(base[1]);
  float y0, y1;
  if (p < 32) {
    const float inv = exp2f((float)p * (-13.287712379549449f / 32.0f));
    const float fr = (float)s * inv;
    const float sn = sinf(fr), cs = cosf(fr);
    y0 = (x0 * cs - x1 * sn) * scale;
    y1 = (x1 * cs + x0 * sn) * scale;
  } else {
    y0 = x0 * scale;
    y1 = x1 * scale;
  }
  base[0] = f2bf(y0);
  base[1] = f2bf(y1);
}

// Flash attention v2. Block = 64 q rows (4 waves x 16 rows). 64-key tiles staged to LDS
// (shared by all 4 waves) via global_load_lds, double-buffered, XOR-swizzled slots so
// DMA lane-contiguity and conflict-free b128 reads coexist. One barrier per tile;
// prefetch of t+1 issued right after the barrier. Heavy-first 1D grid (qt descending).
__global__ __launch_bounds__(256, 2) void attn_kernel(
    const u16* __restrict__ q, const u16* __restrict__ k,
    const u16* __restrict__ vT, u16* __restrict__ out) {
  __shared__ __attribute__((aligned(16))) u16 Ks[2][64 * 128];  // [key][slot^], 16KB each
  __shared__ __attribute__((aligned(16))) u16 Vs[2][128 * 64];  // [dim][slot^], 16KB each
  __shared__ __attribute__((aligned(16))) u16 Ps[4][16 * 88];   // per-wave P transpose
  const int tid = threadIdx.x;
  const int w = tid >> 6, lane = tid & 63;
  const int quad = lane >> 4, l16 = lane & 15;
  const int qt = 31 - (blockIdx.x >> 5);  // heavy tiles dispatched first
  const int bh = blockIdx.x & 31;
  const int qbase = qt * 64 + w * 16;

  const u16* qp = q + ((long)bh * 2048 + qbase) * 128;
  const u16* kp = k + (long)bh * 2048 * 128;
  const u16* vp = vT + (long)bh * 128 * 2048;

  s16x8 qf[4];  // A-frag: Q[m=l16][kdim = c*32 + quad*8 + j]
#pragma unroll
  for (int c = 0; c < 4; ++c)
    qf[c] = *(const s16x8*)(qp + l16 * 128 + c * 32 + quad * 8);

  f32x4 acc[8];
#pragma unroll
  for (int d = 0; d < 8; ++d) acc[d] = f32x4{0.f, 0.f, 0.f, 0.f};
  float mrun[4], lrun[4];
#pragma unroll
  for (int r = 0; r < 4; ++r) { mrun[r] = -1e30f; lrun[r] = 0.f; }

  // stage one 64-key tile into buffer `buf`; wave w: keys [w*16,w*16+16), dims [w*32,w*32+32)
  auto stage = [&](int k0, int buf) {
    const int ko = lane >> 4, cl = lane & 15;
#pragma unroll
    for (int i = 0; i < 4; ++i) {
      const int keyt = w * 16 + i * 4;       // uniform base key of this 1KB chunk
      const int key = keyt + ko;             // this lane's key
      async_copy16(kp + (long)(k0 + key) * 128 + ((cl ^ (key & 15)) << 3),
                   &Ks[buf][keyt * 128]);
    }
    const int ld = lane >> 3, c8 = lane & 7;
#pragma unroll
    for (int i = 0; i < 4; ++i) {
      const int db = w * 32 + i * 8;         // uniform base dim of this 1KB chunk
      const int d = db + ld;
      async_copy16(vp + (long)d * 2048 + k0 + ((c8 ^ (d & 7)) << 3),
                   &Vs[buf][db * 64]);
    }
  };

  stage(0, 0);

  for (int t = 0; t <= qt; ++t) {
    const int k0 = t * 64;
    const u16* Ksc = Ks[t & 1];
    const u16* Vsc = Vs[t & 1];
    __builtin_amdgcn_s_waitcnt(0x0f70);  // vmcnt(0) only: my tile-t DMA done
    __syncthreads();                     // all waves' DMA done; prev buf free
    if (t < qt) stage(k0 + 64, (t + 1) & 1);

    // QK^T: sc[g] over keys k0+g*16+l16
    f32x4 sc[4];
#pragma unroll
    for (int g = 0; g < 4; ++g) {
      sc[g] = f32x4{0.f, 0.f, 0.f, 0.f};
#pragma unroll
      for (int c = 0; c < 4; ++c) {
        const s16x8 kf = *(const s16x8*)(
            &Ksc[(g * 16 + l16) * 128 + ((((c << 2) + quad) ^ l16) << 3)]);
        sc[g] = __builtin_amdgcn_mfma_f32_16x16x32_bf16(qf[c], kf, sc[g], 0, 0, 0);
      }
    }
    if (t == qt) {  // only the diagonal tile needs masking (wave-uniform branch)
#pragma unroll
      for (int g = 0; g < 4; ++g) {
        const int col = k0 + g * 16 + l16;
#pragma unroll
        for (int r = 0; r < 4; ++r)
          if (col > qbase + quad * 4 + r) sc[g][r] = -1e30f;
      }
    }
    // online softmax (exp2 domain)
    float p[4][4], alpha[4];
#pragma unroll
    for (int r = 0; r < 4; ++r) {
      float mx = fmaxf(fmaxf(sc[0][r], sc[1][r]), fmaxf(sc[2][r], sc[3][r]));
#pragma unroll
      for (int off = 1; off < 16; off <<= 1) mx = fmaxf(mx, __shfl_xor(mx, off, 64));
      const float mnew = fmaxf(mrun[r], mx);
      alpha[r] = exp2f(mrun[r] - mnew);
      mrun[r] = mnew;
      float sm = 0.f;
#pragma unroll
      for (int g = 0; g < 4; ++g) { p[g][r] = exp2f(sc[g][r] - mnew); sm += p[g][r]; }
#pragma unroll
      for (int off = 1; off < 16; off <<= 1) sm += __shfl_xor(sm, off, 64);
      lrun[r] = lrun[r] * alpha[r] + sm;
    }
#pragma unroll
    for (int d = 0; d < 8; ++d)
#pragma unroll
      for (int r = 0; r < 4; ++r) acc[d][r] *= alpha[r];
    // P: C-layout -> A-layout via per-wave LDS (stride 88 u16: 16B-aligned rows, bank-spread)
#pragma unroll
    for (int r = 0; r < 4; ++r)
#pragma unroll
      for (int g = 0; g < 4; ++g)
        Ps[w][(quad * 4 + r) * 88 + g * 16 + l16] = f2bf(p[g][r]);
    __builtin_amdgcn_s_waitcnt(0xc07f);  // lgkmcnt(0) only: DS writes visible to my wave
#pragma unroll
    for (int kk = 0; kk < 2; ++kk) {
      const s16x8 pf = *(const s16x8*)(&Ps[w][l16 * 88 + kk * 32 + quad * 8]);
#pragma unroll
      for (int dd = 0; dd < 8; ++dd) {
        const s16x8 vf = *(const s16x8*)(
            &Vsc[(dd * 16 + l16) * 64 + ((((kk << 2) + quad) ^ (l16 & 7)) << 3)]);
        acc[dd] = __builtin_amdgcn_mfma_f32_16x16x32_bf16(pf, vf, acc[dd], 0, 0, 0);
      }
    }
  }

  const int b = bh >> 4, h = bh & 15;
  u16* op = out + ((long)b * 2048 + qbase) * 2048 + h * 128;
#pragma unroll
  for (int d = 0; d < 8; ++d)
#pragma unroll
    for (int r = 0; r < 4; ++r) {
      const float v = acc[d][r] / lrun[r];
      op[(long)(quad * 4 + r) * 2048 + d * 16 + l16] = f2bf(v);
    }
}

extern "C" void kernel_launch(void* const* d_in, const int* in_sizes, int n_in,
                              void* d_out, int out_size, void* d_ws, size_t ws_size,
                              hipStream_t stream) {
  const float* hidden = (const float*)d_in[0];  // [2,2048,2048]
  const float* w_qkv = (const float*)d_in[1];   // [6144,2048]
  const float* w_out = (const float*)d_in[2];   // [2048,2048]
  float* out = (float*)d_out;                   // [2,2048,2048] fp32
  char* ws = (char*)d_ws;

  // workspace layout (112 MB total, all 16B aligned)
  u16* hid_b  = (u16*)(ws + (size_t)0);          // hidden bf16
  u16* wqkv_b = (u16*)(ws + (size_t)16777216);   // w_qkv bf16
  u16* wout_b = (u16*)(ws + (size_t)41943040);   // w_out bf16
  u16* qb     = (u16*)(ws + (size_t)50331648);   // q [B,H,S,D]
  u16* kb     = (u16*)(ws + (size_t)67108864);   // k [B,H,S,D]
  u16* vb     = (u16*)(ws + (size_t)83886080);   // v^T [B,H,D,S]
  u16* ao     = (u16*)(ws + (size_t)100663296);  // attn out [B,S,E]

  cast_bf16_kernel<<<8192, 256, 0, stream>>>(hidden, hid_b, 2097152);
  cast_bf16_kernel<<<12288, 256, 0, stream>>>(w_qkv, wqkv_b, 3145728);
  cast_bf16_kernel<<<4096, 256, 0, stream>>>(w_out, wout_b, 1048576);

  gemm_bt_kernel<1><<<dim3(48, 32), 256, 0, stream>>>(hid_b, wqkv_b, 2048, 6144,
                                                      nullptr, qb, kb, vb);
  rope_kernel<<<dim3(16384, 2), 256, 0, stream>>>(qb, kb);
  attn_kernel<<<1024, 256, 0, stream>>>(qb, kb, vb, ao);
  gemm_bt_kernel<0><<<dim3(16, 32), 256, 0, stream>>>(ao, wout_b, 2048, 2048,
                                                      out, nullptr, nullptr, nullptr);
}

// Round 3
// 438.507 us; speedup vs baseline: 1.8469x; 1.0170x over previous
//
#include <hip/hip_runtime.h>

typedef unsigned short u16;
typedef unsigned int u32;
typedef __attribute__((ext_vector_type(4))) float f32x4;
typedef __attribute__((ext_vector_type(8))) short s16x8;

#define DEVI static __device__ __forceinline__

// B=2, S=2048, E=2048, H=16, D=128, MP=4, local=512; qkv cols: [q(512) v(512) k(512)] x4
// scale (1/sqrt(128))*log2(e) folded into q during rope; softmax in exp2 domain.

DEVI u16 f2bf(float f) {
  u32 u = __float_as_uint(f);
  return (u16)((u + 0x7FFFu + ((u >> 16) & 1u)) >> 16);  // round-to-nearest-even
}
DEVI float bf2f(u16 h) { return __uint_as_float(((u32)h) << 16); }

DEVI void async_copy16(const u16* g, u16* l) {
  // dest = wave-uniform LDS base + lane*16 (gfx950 global_load_lds_dwordx4)
  __builtin_amdgcn_global_load_lds((__attribute__((address_space(1))) void*)g,
                                   (__attribute__((address_space(3))) void*)l, 16, 0, 0);
}

// fused fp32->bf16 cast of all three inputs
__global__ __launch_bounds__(256) void cast3_kernel(
    const float* __restrict__ s0, u16* __restrict__ d0, int n0,
    const float* __restrict__ s1, u16* __restrict__ d1, int n1,
    const float* __restrict__ s2, u16* __restrict__ d2, int n2) {
  int i = blockIdx.x * 256 + threadIdx.x;
  const float* s;
  u16* d;
  if (i < n0) {
    s = s0; d = d0;
  } else if (i < n0 + n1) {
    s = s1; d = d1; i -= n0;
  } else if (i < n0 + n1 + n2) {
    s = s2; d = d2; i -= n0 + n1;
  } else {
    return;
  }
  const float4 v = ((const float4*)s)[i];
  ushort4 o;
  o.x = f2bf(v.x); o.y = f2bf(v.y); o.z = f2bf(v.z); o.w = f2bf(v.w);
  ((ushort4*)d)[i] = o;
}

// C[m,n] = sum_k A[m,k]*B[n,k]; A,B row-major bf16 with K contiguous (B^T GEMM).
// 128x128 block tile, BK=32, 4 waves as 2x2 of 64x64, 16x16x32 MFMA 4x4 frags/wave.
// LDS double-buffered (1 barrier/K-step, prefetch t+1 during compute of t) and
// XOR-swizzled (chunk c of row r stored at c^((r>>1)&3); read-side swizzle is
// lane-constant since (R>>1)&3 == (l16>>1)&3) -> 2 lanes/bank-group = conflict-free.
// EPI=0: C fp32 plain store.  EPI=1: scatter qkv -> q[B,H,S,D], k[B,H,S,D], v^T[B,H,D,S].
template <int EPI>
__global__ __launch_bounds__(256, 2) void gemm_bt_kernel(
    const u16* __restrict__ A, const u16* __restrict__ Bm, int K, int N,
    float* __restrict__ C, u16* __restrict__ qo, u16* __restrict__ ko, u16* __restrict__ vo) {
  __shared__ __attribute__((aligned(16))) u16 As[2][128 * 32];
  __shared__ __attribute__((aligned(16))) u16 Bs[2][128 * 32];
  const int tid = threadIdx.x;
  const int w = tid >> 6, lane = tid & 63;
  const int quad = lane >> 4, l16 = lane & 15;
  const int wrow = (w >> 1) * 64, wcol = (w & 1) * 64;
  const long tileM = (long)blockIdx.y * 128;
  const long tileN = (long)blockIdx.x * 128;

  f32x4 acc[4][4];
#pragma unroll
  for (int i = 0; i < 4; ++i)
#pragma unroll
    for (int j = 0; j < 4; ++j) acc[i][j] = f32x4{0.f, 0.f, 0.f, 0.f};

  // staging: wave w covers tile rows [w*32, w*32+32) in two 16-row chunks.
  // lane -> row r0+(lane>>2), LDS chunk pos p=lane&3; global col chunk = p ^ ((row>>1)&3).
  const u16* aptr[2];
  const u16* bptr[2];
  int ldso[2];
#pragma unroll
  for (int c = 0; c < 2; ++c) {
    const int r0 = (w * 2 + c) * 16;
    const int row = r0 + (lane >> 2);
    const int colsw = (((lane & 3) ^ ((row >> 1) & 3)) << 3);
    aptr[c] = A + (tileM + row) * (long)K + colsw;
    bptr[c] = Bm + (tileN + row) * (long)K + colsw;
    ldso[c] = r0 * 32;
  }

  auto stage = [&](int k0, int buf) {
#pragma unroll
    for (int c = 0; c < 2; ++c) {
      async_copy16(aptr[c] + k0, &As[buf][ldso[c]]);
      async_copy16(bptr[c] + k0, &Bs[buf][ldso[c]]);
    }
  };

  stage(0, 0);

  // read-side swizzled chunk position (lane-constant)
  const int psw = (quad ^ ((l16 >> 1) & 3)) << 3;

  int buf = 0;
  for (int k0 = 0; k0 < K; k0 += 32) {
    __builtin_amdgcn_s_waitcnt(0x0f70);  // vmcnt(0): my tile-t DMA done
    __syncthreads();                     // everyone's DMA done; prev buf free
    if (k0 + 32 < K) stage(k0 + 32, buf ^ 1);

    s16x8 af[4], bfr[4];
#pragma unroll
    for (int i = 0; i < 4; ++i)
      af[i] = *(const s16x8*)(&As[buf][(wrow + i * 16 + l16) * 32 + psw]);
#pragma unroll
    for (int j = 0; j < 4; ++j)
      bfr[j] = *(const s16x8*)(&Bs[buf][(wcol + j * 16 + l16) * 32 + psw]);
#pragma unroll
    for (int i = 0; i < 4; ++i)
#pragma unroll
      for (int j = 0; j < 4; ++j)
        acc[i][j] = __builtin_amdgcn_mfma_f32_16x16x32_bf16(af[i], bfr[j], acc[i][j], 0, 0, 0);
    buf ^= 1;
  }

#pragma unroll
  for (int i = 0; i < 4; ++i) {
#pragma unroll
    for (int j = 0; j < 4; ++j) {
#pragma unroll
      for (int r = 0; r < 4; ++r) {
        const long row = tileM + wrow + i * 16 + quad * 4 + r;  // C row = quad*4+reg
        const long col = tileN + wcol + j * 16 + l16;           // C col = lane&15
        const float v = acc[i][j][r];
        if (EPI == 0) {
          C[row * N + col] = v;
        } else {
          const int b = (int)(row >> 11), s = (int)(row & 2047);
          const int cl = (int)col;
          const int mp = cl / 1536;
          const int cc = cl - mp * 1536;
          const int part = cc >> 9;         // 0:q 1:v 2:k
          const int idx = cc & 511;
          const int head = mp * 4 + (idx >> 7);
          const int dim = idx & 127;
          const long bh = b * 16 + head;
          const u16 bv = f2bf(v);
          if (part == 0)      qo[(bh * 2048 + s) * 128 + dim] = bv;
          else if (part == 2) ko[(bh * 2048 + s) * 128 + dim] = bv;
          else                vo[(bh * 128 + dim) * 2048 + s] = bv;  // v stored transposed
        }
      }
    }
  }
}

// In-place rope on q (blockIdx.y=0, also applies log2e/sqrt(D)) and k (blockIdx.y=1).
__global__ __launch_bounds__(256) void rope_kernel(u16* __restrict__ q, u16* __restrict__ k) {
  const int tid = threadIdx.x;
  const long row = (long)blockIdx.x * 4 + (tid >> 6);  // row in [0, B*H*S)
  const int p = tid & 63;                              // pair index 0..63
  const int s = (int)(row & 2047);                     // position
  u16* base = (blockIdx.y == 0 ? q : k) + row * 128 + p * 2;
  // q scale = 1/sqrt(128) * log2(e)  (softmax runs in exp2 domain)
  const float scale = (blockIdx.y == 0) ? 0.12751743f : 1.0f;
  const float x0 = bf2f(base[0]), x1 = bf2f(base[1]);
  float y0, y1;
  if (p < 32) {
    const float inv = exp2f((float)p * (-13.287712379549449f / 32.0f));
    const float fr = (float)s * inv;
    const float sn = sinf(fr), cs = cosf(fr);
    y0 = (x0 * cs - x1 * sn) * scale;
    y1 = (x1 * cs + x0 * sn) * scale;
  } else {
    y0 = x0 * scale;
    y1 = x1 * scale;
  }
  base[0] = f2bf(y0);
  base[1] = f2bf(y1);
}

// Flash attention. Block = 64 q rows (4 waves x 16 rows). 64-key tiles staged to LDS
// (shared by all 4 waves) via global_load_lds, double-buffered, XOR-swizzled slots.
// One barrier per tile; prefetch of t+1 issued right after the barrier.
// Heavy-first 1D grid (qt descending).
__global__ __launch_bounds__(256, 2) void attn_kernel(
    const u16* __restrict__ q, const u16* __restrict__ k,
    const u16* __restrict__ vT, u16* __restrict__ out) {
  __shared__ __attribute__((aligned(16))) u16 Ks[2][64 * 128];  // [key][slot^], 16KB each
  __shared__ __attribute__((aligned(16))) u16 Vs[2][128 * 64];  // [dim][slot^], 16KB each
  __shared__ __attribute__((aligned(16))) u16 Ps[4][16 * 88];   // per-wave P transpose
  const int tid = threadIdx.x;
  const int w = tid >> 6, lane = tid & 63;
  const int quad = lane >> 4, l16 = lane & 15;
  const int qt = 31 - (blockIdx.x >> 5);  // heavy tiles dispatched first
  const int bh = blockIdx.x & 31;
  const int qbase = qt * 64 + w * 16;

  const u16* qp = q + ((long)bh * 2048 + qbase) * 128;
  const u16* kp = k + (long)bh * 2048 * 128;
  const u16* vp = vT + (long)bh * 128 * 2048;

  s16x8 qf[4];  // A-frag: Q[m=l16][kdim = c*32 + quad*8 + j]
#pragma unroll
  for (int c = 0; c < 4; ++c)
    qf[c] = *(const s16x8*)(qp + l16 * 128 + c * 32 + quad * 8);

  f32x4 acc[8];
#pragma unroll
  for (int d = 0; d < 8; ++d) acc[d] = f32x4{0.f, 0.f, 0.f, 0.f};
  float mrun[4], lrun[4];
#pragma unroll
  for (int r = 0; r < 4; ++r) { mrun[r] = -1e30f; lrun[r] = 0.f; }

  // stage one 64-key tile into buffer `buf`; wave w: keys [w*16,w*16+16), dims [w*32,w*32+32)
  auto stage = [&](int k0, int buf) {
    const int ko = lane >> 4, cl = lane & 15;
#pragma unroll
    for (int i = 0; i < 4; ++i) {
      const int keyt = w * 16 + i * 4;       // uniform base key of this 1KB chunk
      const int key = keyt + ko;             // this lane's key
      async_copy16(kp + (long)(k0 + key) * 128 + ((cl ^ (key & 15)) << 3),
                   &Ks[buf][keyt * 128]);
    }
    const int ld = lane >> 3, c8 = lane & 7;
#pragma unroll
    for (int i = 0; i < 4; ++i) {
      const int db = w * 32 + i * 8;         // uniform base dim of this 1KB chunk
      const int d = db + ld;
      async_copy16(vp + (long)d * 2048 + k0 + ((c8 ^ (d & 7)) << 3),
                   &Vs[buf][db * 64]);
    }
  };

  stage(0, 0);

  for (int t = 0; t <= qt; ++t) {
    const int k0 = t * 64;
    const u16* Ksc = Ks[t & 1];
    const u16* Vsc = Vs[t & 1];
    __builtin_amdgcn_s_waitcnt(0x0f70);  // vmcnt(0) only: my tile-t DMA done
    __syncthreads();                     // all waves' DMA done; prev buf free
    if (t < qt) stage(k0 + 64, (t + 1) & 1);

    // QK^T: sc[g] over keys k0+g*16+l16
    f32x4 sc[4];
#pragma unroll
    for (int g = 0; g < 4; ++g) {
      sc[g] = f32x4{0.f, 0.f, 0.f, 0.f};
#pragma unroll
      for (int c = 0; c < 4; ++c) {
        const s16x8 kf = *(const s16x8*)(
            &Ksc[(g * 16 + l16) * 128 + ((((c << 2) + quad) ^ l16) << 3)]);
        sc[g] = __builtin_amdgcn_mfma_f32_16x16x32_bf16(qf[c], kf, sc[g], 0, 0, 0);
      }
    }
    if (t == qt) {  // only the diagonal tile needs masking (wave-uniform branch)
#pragma unroll
      for (int g = 0; g < 4; ++g) {
        const int col = k0 + g * 16 + l16;
#pragma unroll
        for (int r = 0; r < 4; ++r)
          if (col > qbase + quad * 4 + r) sc[g][r] = -1e30f;
      }
    }
    // online softmax (exp2 domain)
    float p[4][4], alpha[4];
#pragma unroll
    for (int r = 0; r < 4; ++r) {
      float mx = fmaxf(fmaxf(sc[0][r], sc[1][r]), fmaxf(sc[2][r], sc[3][r]));
#pragma unroll
      for (int off = 1; off < 16; off <<= 1) mx = fmaxf(mx, __shfl_xor(mx, off, 64));
      const float mnew = fmaxf(mrun[r], mx);
      alpha[r] = exp2f(mrun[r] - mnew);
      mrun[r] = mnew;
      float sm = 0.f;
#pragma unroll
      for (int g = 0; g < 4; ++g) { p[g][r] = exp2f(sc[g][r] - mnew); sm += p[g][r]; }
#pragma unroll
      for (int off = 1; off < 16; off <<= 1) sm += __shfl_xor(sm, off, 64);
      lrun[r] = lrun[r] * alpha[r] + sm;
    }
#pragma unroll
    for (int d = 0; d < 8; ++d)
#pragma unroll
      for (int r = 0; r < 4; ++r) acc[d][r] *= alpha[r];
    // P: C-layout -> A-layout via per-wave LDS (stride 88 u16: 16B-aligned rows, bank-spread)
#pragma unroll
    for (int r = 0; r < 4; ++r)
#pragma unroll
      for (int g = 0; g < 4; ++g)
        Ps[w][(quad * 4 + r) * 88 + g * 16 + l16] = f2bf(p[g][r]);
    __builtin_amdgcn_s_waitcnt(0xc07f);  // lgkmcnt(0) only: DS writes visible to my wave
#pragma unroll
    for (int kk = 0; kk < 2; ++kk) {
      const s16x8 pf = *(const s16x8*)(&Ps[w][l16 * 88 + kk * 32 + quad * 8]);
#pragma unroll
      for (int dd = 0; dd < 8; ++dd) {
        const s16x8 vf = *(const s16x8*)(
            &Vsc[(dd * 16 + l16) * 64 + ((((kk << 2) + quad) ^ (l16 & 7)) << 3)]);
        acc[dd] = __builtin_amdgcn_mfma_f32_16x16x32_bf16(pf, vf, acc[dd], 0, 0, 0);
      }
    }
  }

  const int b = bh >> 4, h = bh & 15;
  u16* op = out + ((long)b * 2048 + qbase) * 2048 + h * 128;
#pragma unroll
  for (int d = 0; d < 8; ++d)
#pragma unroll
    for (int r = 0; r < 4; ++r) {
      const float v = acc[d][r] / lrun[r];
      op[(long)(quad * 4 + r) * 2048 + d * 16 + l16] = f2bf(v);
    }
}

extern "C" void kernel_launch(void* const* d_in, const int* in_sizes, int n_in,
                              void* d_out, int out_size, void* d_ws, size_t ws_size,
                              hipStream_t stream) {
  const float* hidden = (const float*)d_in[0];  // [2,2048,2048]
  const float* w_qkv = (const float*)d_in[1];   // [6144,2048]
  const float* w_out = (const float*)d_in[2];   // [2048,2048]
  float* out = (float*)d_out;                   // [2,2048,2048] fp32
  char* ws = (char*)d_ws;

  // workspace layout (112 MB total, all 16B aligned)
  u16* hid_b  = (u16*)(ws + (size_t)0);          // hidden bf16
  u16* wqkv_b = (u16*)(ws + (size_t)16777216);   // w_qkv bf16
  u16* wout_b = (u16*)(ws + (size_t)41943040);   // w_out bf16
  u16* qb     = (u16*)(ws + (size_t)50331648);   // q [B,H,S,D]
  u16* kb     = (u16*)(ws + (size_t)67108864);   // k [B,H,S,D]
  u16* vb     = (u16*)(ws + (size_t)83886080);   // v^T [B,H,D,S]
  u16* ao     = (u16*)(ws + (size_t)100663296);  // attn out [B,S,E]

  cast3_kernel<<<24576, 256, 0, stream>>>(hidden, hid_b, 2097152,
                                          w_qkv, wqkv_b, 3145728,
                                          w_out, wout_b, 1048576);

  gemm_bt_kernel<1><<<dim3(48, 32), 256, 0, stream>>>(hid_b, wqkv_b, 2048, 6144,
                                                      nullptr, qb, kb, vb);
  rope_kernel<<<dim3(16384, 2), 256, 0, stream>>>(qb, kb);
  attn_kernel<<<1024, 256, 0, stream>>>(qb, kb, vb, ao);
  gemm_bt_kernel<0><<<dim3(16, 32), 256, 0, stream>>>(ao, wout_b, 2048, 2048,
                                                      out, nullptr, nullptr, nullptr);
}

// Round 4
// 437.886 us; speedup vs baseline: 1.8495x; 1.0014x over previous
//
#include <hip/hip_runtime.h>

typedef unsigned short u16;
typedef unsigned int u32;
typedef __attribute__((ext_vector_type(4))) float f32x4;
typedef __attribute__((ext_vector_type(8))) short s16x8;

#define DEVI static __device__ __forceinline__

// B=2, S=2048, E=2048, H=16, D=128, MP=4, local=512; qkv cols: [q(512) v(512) k(512)] x4
// scale (1/sqrt(128))*log2(e) folded into q during rope; softmax in exp2 domain.

DEVI u16 f2bf(float f) {
  u32 u = __float_as_uint(f);
  return (u16)((u + 0x7FFFu + ((u >> 16) & 1u)) >> 16);  // round-to-nearest-even
}
DEVI float bf2f(u16 h) { return __uint_as_float(((u32)h) << 16); }

DEVI void async_copy16(const u16* g, u16* l) {
  // dest = wave-uniform LDS base + lane*16 (gfx950 global_load_lds_dwordx4)
  __builtin_amdgcn_global_load_lds((__attribute__((address_space(1))) void*)g,
                                   (__attribute__((address_space(3))) void*)l, 16, 0, 0);
}

// fused fp32->bf16 cast of all three inputs
__global__ __launch_bounds__(256) void cast3_kernel(
    const float* __restrict__ s0, u16* __restrict__ d0, int n0,
    const float* __restrict__ s1, u16* __restrict__ d1, int n1,
    const float* __restrict__ s2, u16* __restrict__ d2, int n2) {
  int i = blockIdx.x * 256 + threadIdx.x;
  const float* s;
  u16* d;
  if (i < n0) {
    s = s0; d = d0;
  } else if (i < n0 + n1) {
    s = s1; d = d1; i -= n0;
  } else if (i < n0 + n1 + n2) {
    s = s2; d = d2; i -= n0 + n1;
  } else {
    return;
  }
  const float4 v = ((const float4*)s)[i];
  ushort4 o;
  o.x = f2bf(v.x); o.y = f2bf(v.y); o.z = f2bf(v.z); o.w = f2bf(v.w);
  ((ushort4*)d)[i] = o;
}

// C[m,n] = sum_k A[m,k]*B[n,k]; A,B row-major bf16 with K contiguous (B^T GEMM).
// 128x128 block tile, BK=32, 4 waves as 2x2 of 64x64, 16x16x32 MFMA 4x4 frags/wave.
// K-loop: 3-deep LDS pipeline (48KB), AITER-style: s_waitcnt vmcnt(4) keeps tile t+1's
// DMA in flight across a RAW s_barrier (no __syncthreads -> no compiler vmcnt(0) drain).
// XOR-swizzled LDS (chunk c of row r at c^((r>>1)&3)); read swizzle is lane-constant.
// EPI=0: C fp32 plain store.  EPI=1: scatter qkv -> q[B,H,S,D], k[B,H,S,D], v^T[B,H,D,S].
template <int EPI>
__global__ __launch_bounds__(256, 3) void gemm_bt_kernel(
    const u16* __restrict__ A, const u16* __restrict__ Bm, int K, int N,
    float* __restrict__ C, u16* __restrict__ qo, u16* __restrict__ ko, u16* __restrict__ vo) {
  __shared__ __attribute__((aligned(16))) u16 As[3][128 * 32];  // 8KB each
  __shared__ __attribute__((aligned(16))) u16 Bs[3][128 * 32];  // 8KB each
  const int tid = threadIdx.x;
  const int w = tid >> 6, lane = tid & 63;
  const int quad = lane >> 4, l16 = lane & 15;
  const int wrow = (w >> 1) * 64, wcol = (w & 1) * 64;
  const long tileM = (long)blockIdx.y * 128;
  const long tileN = (long)blockIdx.x * 128;

  f32x4 acc[4][4];
#pragma unroll
  for (int i = 0; i < 4; ++i)
#pragma unroll
    for (int j = 0; j < 4; ++j) acc[i][j] = f32x4{0.f, 0.f, 0.f, 0.f};

  // staging: wave w covers tile rows [w*32, w*32+32) in two 16-row chunks.
  // lane -> row r0+(lane>>2), LDS chunk pos p=lane&3; global col chunk = p ^ ((row>>1)&3).
  const u16* aptr[2];
  const u16* bptr[2];
  int ldso[2];
#pragma unroll
  for (int c = 0; c < 2; ++c) {
    const int r0 = (w * 2 + c) * 16;
    const int row = r0 + (lane >> 2);
    const int colsw = (((lane & 3) ^ ((row >> 1) & 3)) << 3);
    aptr[c] = A + (tileM + row) * (long)K + colsw;
    bptr[c] = Bm + (tileN + row) * (long)K + colsw;
    ldso[c] = r0 * 32;
  }

  auto stage = [&](int k0, int buf) {
    // 4 DMAs per wave per tile (2 A + 2 B) -> vmcnt granularity of 4
#pragma unroll
    for (int c = 0; c < 2; ++c) {
      async_copy16(aptr[c] + k0, &As[buf][ldso[c]]);
      async_copy16(bptr[c] + k0, &Bs[buf][ldso[c]]);
    }
  };

  stage(0, 0);
  stage(32, 1);

  // read-side swizzled chunk position (lane-constant)
  const int psw = (quad ^ ((l16 >> 1) & 3)) << 3;

  int bt = 0;
  for (int k0 = 0; k0 < K; k0 += 32) {
    if (k0 + 32 < K)
      __builtin_amdgcn_s_waitcnt(0x0f74);  // vmcnt(4): tile t landed, t+1 in flight
    else
      __builtin_amdgcn_s_waitcnt(0x0f70);  // last tile: vmcnt(0)
    __builtin_amdgcn_s_barrier();          // raw barrier: no compiler-forced drain
    if (k0 + 64 < K) stage(k0 + 64, bt == 0 ? 2 : bt - 1);  // overwrite t-1's buffer

    s16x8 af[4], bfr[4];
#pragma unroll
    for (int i = 0; i < 4; ++i)
      af[i] = *(const s16x8*)(&As[bt][(wrow + i * 16 + l16) * 32 + psw]);
#pragma unroll
    for (int j = 0; j < 4; ++j)
      bfr[j] = *(const s16x8*)(&Bs[bt][(wcol + j * 16 + l16) * 32 + psw]);
#pragma unroll
    for (int i = 0; i < 4; ++i)
#pragma unroll
      for (int j = 0; j < 4; ++j)
        acc[i][j] = __builtin_amdgcn_mfma_f32_16x16x32_bf16(af[i], bfr[j], acc[i][j], 0, 0, 0);
    bt = bt == 2 ? 0 : bt + 1;
  }

#pragma unroll
  for (int i = 0; i < 4; ++i) {
#pragma unroll
    for (int j = 0; j < 4; ++j) {
#pragma unroll
      for (int r = 0; r < 4; ++r) {
        const long row = tileM + wrow + i * 16 + quad * 4 + r;  // C row = quad*4+reg
        const long col = tileN + wcol + j * 16 + l16;           // C col = lane&15
        const float v = acc[i][j][r];
        if (EPI == 0) {
          C[row * N + col] = v;
        } else {
          const int b = (int)(row >> 11), s = (int)(row & 2047);
          const int cl = (int)col;
          const int mp = cl / 1536;
          const int cc = cl - mp * 1536;
          const int part = cc >> 9;         // 0:q 1:v 2:k
          const int idx = cc & 511;
          const int head = mp * 4 + (idx >> 7);
          const int dim = idx & 127;
          const long bh = b * 16 + head;
          const u16 bv = f2bf(v);
          if (part == 0)      qo[(bh * 2048 + s) * 128 + dim] = bv;
          else if (part == 2) ko[(bh * 2048 + s) * 128 + dim] = bv;
          else                vo[(bh * 128 + dim) * 2048 + s] = bv;  // v stored transposed
        }
      }
    }
  }
}

// In-place rope on q (blockIdx.y=0, also applies log2e/sqrt(D)) and k (blockIdx.y=1).
__global__ __launch_bounds__(256) void rope_kernel(u16* __restrict__ q, u16* __restrict__ k) {
  const int tid = threadIdx.x;
  const long row = (long)blockIdx.x * 4 + (tid >> 6);  // row in [0, B*H*S)
  const int p = tid & 63;                              // pair index 0..63
  const int s = (int)(row & 2047);                     // position
  u16* base = (blockIdx.y == 0 ? q : k) + row * 128 + p * 2;
  // q scale = 1/sqrt(128) * log2(e)  (softmax runs in exp2 domain)
  const float scale = (blockIdx.y == 0) ? 0.12751743f : 1.0f;
  const float x0 = bf2f(base[0]), x1 = bf2f(base[1]);
  float y0, y1;
  if (p < 32) {
    const float inv = exp2f((float)p * (-13.287712379549449f / 32.0f));
    const float fr = (float)s * inv;
    const float sn = sinf(fr), cs = cosf(fr);
    y0 = (x0 * cs - x1 * sn) * scale;
    y1 = (x1 * cs + x0 * sn) * scale;
  } else {
    y0 = x0 * scale;
    y1 = x1 * scale;
  }
  base[0] = f2bf(y0);
  base[1] = f2bf(y1);
}

// Flash attention. Block = 64 q rows (4 waves x 16 rows). 64-key tiles staged to LDS
// (shared by all 4 waves) via global_load_lds, double-buffered, XOR-swizzled slots.
// One barrier per tile; prefetch of t+1 issued right after the barrier.
// Heavy-first 1D grid (qt descending).
__global__ __launch_bounds__(256, 2) void attn_kernel(
    const u16* __restrict__ q, const u16* __restrict__ k,
    const u16* __restrict__ vT, u16* __restrict__ out) {
  __shared__ __attribute__((aligned(16))) u16 Ks[2][64 * 128];  // [key][slot^], 16KB each
  __shared__ __attribute__((aligned(16))) u16 Vs[2][128 * 64];  // [dim][slot^], 16KB each
  __shared__ __attribute__((aligned(16))) u16 Ps[4][16 * 88];   // per-wave P transpose
  const int tid = threadIdx.x;
  const int w = tid >> 6, lane = tid & 63;
  const int quad = lane >> 4, l16 = lane & 15;
  const int qt = 31 - (blockIdx.x >> 5);  // heavy tiles dispatched first
  const int bh = blockIdx.x & 31;
  const int qbase = qt * 64 + w * 16;

  const u16* qp = q + ((long)bh * 2048 + qbase) * 128;
  const u16* kp = k + (long)bh * 2048 * 128;
  const u16* vp = vT + (long)bh * 128 * 2048;

  s16x8 qf[4];  // A-frag: Q[m=l16][kdim = c*32 + quad*8 + j]
#pragma unroll
  for (int c = 0; c < 4; ++c)
    qf[c] = *(const s16x8*)(qp + l16 * 128 + c * 32 + quad * 8);

  f32x4 acc[8];
#pragma unroll
  for (int d = 0; d < 8; ++d) acc[d] = f32x4{0.f, 0.f, 0.f, 0.f};
  float mrun[4], lrun[4];
#pragma unroll
  for (int r = 0; r < 4; ++r) { mrun[r] = -1e30f; lrun[r] = 0.f; }

  // stage one 64-key tile into buffer `buf`; wave w: keys [w*16,w*16+16), dims [w*32,w*32+32)
  auto stage = [&](int k0, int buf) {
    const int ko = lane >> 4, cl = lane & 15;
#pragma unroll
    for (int i = 0; i < 4; ++i) {
      const int keyt = w * 16 + i * 4;       // uniform base key of this 1KB chunk
      const int key = keyt + ko;             // this lane's key
      async_copy16(kp + (long)(k0 + key) * 128 + ((cl ^ (key & 15)) << 3),
                   &Ks[buf][keyt * 128]);
    }
    const int ld = lane >> 3, c8 = lane & 7;
#pragma unroll
    for (int i = 0; i < 4; ++i) {
      const int db = w * 32 + i * 8;         // uniform base dim of this 1KB chunk
      const int d = db + ld;
      async_copy16(vp + (long)d * 2048 + k0 + ((c8 ^ (d & 7)) << 3),
                   &Vs[buf][db * 64]);
    }
  };

  stage(0, 0);

  for (int t = 0; t <= qt; ++t) {
    const int k0 = t * 64;
    const u16* Ksc = Ks[t & 1];
    const u16* Vsc = Vs[t & 1];
    __builtin_amdgcn_s_waitcnt(0x0f70);  // vmcnt(0) only: my tile-t DMA done
    __syncthreads();                     // all waves' DMA done; prev buf free
    if (t < qt) stage(k0 + 64, (t + 1) & 1);

    // QK^T: sc[g] over keys k0+g*16+l16
    f32x4 sc[4];
#pragma unroll
    for (int g = 0; g < 4; ++g) {
      sc[g] = f32x4{0.f, 0.f, 0.f, 0.f};
#pragma unroll
      for (int c = 0; c < 4; ++c) {
        const s16x8 kf = *(const s16x8*)(
            &Ksc[(g * 16 + l16) * 128 + ((((c << 2) + quad) ^ l16) << 3)]);
        sc[g] = __builtin_amdgcn_mfma_f32_16x16x32_bf16(qf[c], kf, sc[g], 0, 0, 0);
      }
    }
    if (t == qt) {  // only the diagonal tile needs masking (wave-uniform branch)
#pragma unroll
      for (int g = 0; g < 4; ++g) {
        const int col = k0 + g * 16 + l16;
#pragma unroll
        for (int r = 0; r < 4; ++r)
          if (col > qbase + quad * 4 + r) sc[g][r] = -1e30f;
      }
    }
    // online softmax (exp2 domain)
    float p[4][4], alpha[4];
#pragma unroll
    for (int r = 0; r < 4; ++r) {
      float mx = fmaxf(fmaxf(sc[0][r], sc[1][r]), fmaxf(sc[2][r], sc[3][r]));
#pragma unroll
      for (int off = 1; off < 16; off <<= 1) mx = fmaxf(mx, __shfl_xor(mx, off, 64));
      const float mnew = fmaxf(mrun[r], mx);
      alpha[r] = exp2f(mrun[r] - mnew);
      mrun[r] = mnew;
      float sm = 0.f;
#pragma unroll
      for (int g = 0; g < 4; ++g) { p[g][r] = exp2f(sc[g][r] - mnew); sm += p[g][r]; }
#pragma unroll
      for (int off = 1; off < 16; off <<= 1) sm += __shfl_xor(sm, off, 64);
      lrun[r] = lrun[r] * alpha[r] + sm;
    }
#pragma unroll
    for (int d = 0; d < 8; ++d)
#pragma unroll
      for (int r = 0; r < 4; ++r) acc[d][r] *= alpha[r];
    // P: C-layout -> A-layout via per-wave LDS (stride 88 u16: 16B-aligned rows, bank-spread)
#pragma unroll
    for (int r = 0; r < 4; ++r)
#pragma unroll
      for (int g = 0; g < 4; ++g)
        Ps[w][(quad * 4 + r) * 88 + g * 16 + l16] = f2bf(p[g][r]);
    __builtin_amdgcn_s_waitcnt(0xc07f);  // lgkmcnt(0) only: DS writes visible to my wave
#pragma unroll
    for (int kk = 0; kk < 2; ++kk) {
      const s16x8 pf = *(const s16x8*)(&Ps[w][l16 * 88 + kk * 32 + quad * 8]);
#pragma unroll
      for (int dd = 0; dd < 8; ++dd) {
        const s16x8 vf = *(const s16x8*)(
            &Vsc[(dd * 16 + l16) * 64 + ((((kk << 2) + quad) ^ (l16 & 7)) << 3)]);
        acc[dd] = __builtin_amdgcn_mfma_f32_16x16x32_bf16(pf, vf, acc[dd], 0, 0, 0);
      }
    }
  }

  const int b = bh >> 4, h = bh & 15;
  u16* op = out + ((long)b * 2048 + qbase) * 2048 + h * 128;
#pragma unroll
  for (int d = 0; d < 8; ++d)
#pragma unroll
    for (int r = 0; r < 4; ++r) {
      const float v = acc[d][r] / lrun[r];
      op[(long)(quad * 4 + r) * 2048 + d * 16 + l16] = f2bf(v);
    }
}

extern "C" void kernel_launch(void* const* d_in, const int* in_sizes, int n_in,
                              void* d_out, int out_size, void* d_ws, size_t ws_size,
                              hipStream_t stream) {
  const float* hidden = (const float*)d_in[0];  // [2,2048,2048]
  const float* w_qkv = (const float*)d_in[1];   // [6144,2048]
  const float* w_out = (const float*)d_in[2];   // [2048,2048]
  float* out = (float*)d_out;                   // [2,2048,2048] fp32
  char* ws = (char*)d_ws;

  // workspace layout (112 MB total, all 16B aligned)
  u16* hid_b  = (u16*)(ws + (size_t)0);          // hidden bf16
  u16* wqkv_b = (u16*)(ws + (size_t)16777216);   // w_qkv bf16
  u16* wout_b = (u16*)(ws + (size_t)41943040);   // w_out bf16
  u16* qb     = (u16*)(ws + (size_t)50331648);   // q [B,H,S,D]
  u16* kb     = (u16*)(ws + (size_t)67108864);   // k [B,H,S,D]
  u16* vb     = (u16*)(ws + (size_t)83886080);   // v^T [B,H,D,S]
  u16* ao     = (u16*)(ws + (size_t)100663296);  // attn out [B,S,E]

  cast3_kernel<<<24576, 256, 0, stream>>>(hidden, hid_b, 2097152,
                                          w_qkv, wqkv_b, 3145728,
                                          w_out, wout_b, 1048576);

  gemm_bt_kernel<1><<<dim3(48, 32), 256, 0, stream>>>(hid_b, wqkv_b, 2048, 6144,
                                                      nullptr, qb, kb, vb);
  rope_kernel<<<dim3(16384, 2), 256, 0, stream>>>(qb, kb);
  attn_kernel<<<1024, 256, 0, stream>>>(qb, kb, vb, ao);
  gemm_bt_kernel<0><<<dim3(16, 32), 256, 0, stream>>>(ao, wout_b, 2048, 2048,
                                                      out, nullptr, nullptr, nullptr);
}